// Round 1
// baseline (411.626 us; speedup 1.0000x reference)
//
#include <hip/hip_runtime.h>
#include <hip/hip_bf16.h>
#include <math.h>

// Problem shape (fixed by reference)
#define B  32
#define C  512
#define HW 3136      // 56*56
#define HW4 784      // HW/4 float4 per channel
#define HID 32       // C/16
#define K  256       // C/2, top-k

// ---------------------------------------------------------------------------
// Kernel 1: per-(b,c) mean+max pooling. One block per channel.
// ---------------------------------------------------------------------------
__global__ __launch_bounds__(256) void pool_kernel(const float* __restrict__ x,
                                                   float* __restrict__ y) {
    const int bc = blockIdx.x;
    const float4* xp = (const float4*)(x + (size_t)bc * HW);
    float sum = 0.f;
    float mx  = -INFINITY;
    for (int i = threadIdx.x; i < HW4; i += 256) {
        float4 v = xp[i];
        sum += (v.x + v.y) + (v.z + v.w);
        mx = fmaxf(mx, fmaxf(fmaxf(v.x, v.y), fmaxf(v.z, v.w)));
    }
    // wave-64 butterfly reduce
    for (int off = 32; off > 0; off >>= 1) {
        sum += __shfl_down(sum, off, 64);
        mx   = fmaxf(mx, __shfl_down(mx, off, 64));
    }
    __shared__ float ssum[4], smx[4];
    const int wave = threadIdx.x >> 6;
    const int lane = threadIdx.x & 63;
    if (lane == 0) { ssum[wave] = sum; smx[wave] = mx; }
    __syncthreads();
    if (threadIdx.x == 0) {
        float s = (ssum[0] + ssum[1]) + (ssum[2] + ssum[3]);
        float m = fmaxf(fmaxf(smx[0], smx[1]), fmaxf(smx[2], smx[3]));
        y[bc] = s * (1.0f / (float)HW) + m;
    }
}

// ---------------------------------------------------------------------------
// Kernel 2: per-batch-row MLP + sigmoid + kth-largest threshold + final map.
// One block (256 threads) per batch row; 32 blocks total. All tiny.
// ---------------------------------------------------------------------------
__global__ __launch_bounds__(256) void mlp_kernel(const float* __restrict__ y,
                                                  const float* __restrict__ w1,
                                                  const float* __restrict__ b1,
                                                  const float* __restrict__ prelu_a,
                                                  const float* __restrict__ w2,
                                                  const float* __restrict__ b2,
                                                  const float* __restrict__ rnd,
                                                  float* __restrict__ fmap) {
    const int b = blockIdx.x;
    const int t = threadIdx.x;

    __shared__ float ylds[C];
    __shared__ float hlds[HID];
    __shared__ float y2[C];
    __shared__ float hpart[256];
    __shared__ float thresh;

    ylds[t]       = y[b * C + t];
    ylds[t + 256] = y[b * C + t + 256];
    __syncthreads();

    // h[j] = sum_c y[c] * w1[c][j] + b1[j], PReLU.
    // Split the 512-long dot across 8 chunks of 64; thread t owns (j = t&31, chunk = t>>5).
    {
        const int j = t & 31;
        const int chunk = t >> 5;
        float acc = 0.f;
        const int c0 = chunk * 64;
        #pragma unroll 8
        for (int c = c0; c < c0 + 64; ++c)
            acc += ylds[c] * w1[c * HID + j];
        hpart[t] = acc;
        __syncthreads();
        if (t < HID) {
            float a = ((hpart[t]       + hpart[t + 32]) + (hpart[t + 64]  + hpart[t + 96])) +
                      ((hpart[t + 128] + hpart[t + 160]) + (hpart[t + 192] + hpart[t + 224]));
            a += b1[t];
            const float al = prelu_a[0];
            hlds[t] = (a >= 0.f) ? a : al * a;
        }
    }
    __syncthreads();

    // y2[c] = sigmoid(h . w2[:,c] + b2[c])
    for (int c = t; c < C; c += 256) {
        float acc = b2[c];
        #pragma unroll
        for (int j = 0; j < HID; ++j)
            acc += hlds[j] * w2[j * C + c];
        y2[c] = 1.f / (1.f + expf(-acc));
    }
    __syncthreads();

    // kth-largest (k = K) via rank selection with index tie-break.
    // rank[c] = #{ j : y2[j] > y2[c] } + #{ j < c : y2[j] == y2[c] }
    // The unique element with rank == K-1 is min(top_k).
    for (int c = t; c < C; c += 256) {
        const float v = y2[c];
        int rank = 0;
        for (int j = 0; j < C; ++j) {
            const float u = y2[j];
            rank += (u > v) || (u == v && j < c);
        }
        if (rank == K - 1) thresh = v;
    }
    __syncthreads();

    const float th = thresh;
    for (int c = t; c < C; c += 256) {
        const float v  = y2[c];
        const float rb = (rnd[b * C + c] - 0.5f < 0.f) ? 1.f : 0.f;
        const float mk = (v - th < 0.f) ? 1.f : 0.f;
        // final = mask*rb*v + v*(1-rb)
        fmap[b * C + c] = (rb != 0.f) ? (mk * v) : v;
    }
}

// ---------------------------------------------------------------------------
// Kernel 3: out = x * fmap[channel], one float4 per thread.
// Total float4 = B*C*HW4 = 12,845,056 = 50176 blocks * 256 threads exactly.
// ---------------------------------------------------------------------------
__global__ __launch_bounds__(256) void scale_kernel(const float* __restrict__ x,
                                                    const float* __restrict__ fmap,
                                                    float* __restrict__ out) {
    const int i4 = blockIdx.x * 256 + threadIdx.x;
    const int ch = i4 / HW4;               // magic-multiply division by 784
    const float s = fmap[ch];
    float4 v = ((const float4*)x)[i4];
    v.x *= s; v.y *= s; v.z *= s; v.w *= s;
    ((float4*)out)[i4] = v;
}

extern "C" void kernel_launch(void* const* d_in, const int* in_sizes, int n_in,
                              void* d_out, int out_size, void* d_ws, size_t ws_size,
                              hipStream_t stream) {
    const float* x       = (const float*)d_in[0];
    const float* w1      = (const float*)d_in[1];
    const float* b1      = (const float*)d_in[2];
    const float* prelu_a = (const float*)d_in[3];
    const float* w2      = (const float*)d_in[4];
    const float* b2      = (const float*)d_in[5];
    const float* rnd     = (const float*)d_in[6];
    float* out = (float*)d_out;

    float* y    = (float*)d_ws;            // B*C floats
    float* fmap = y + B * C;               // B*C floats

    pool_kernel<<<B * C, 256, 0, stream>>>(x, y);
    mlp_kernel<<<B, 256, 0, stream>>>(y, w1, b1, prelu_a, w2, b2, rnd, fmap);
    scale_kernel<<<(B * C * HW4) / 256, 256, 0, stream>>>(x, fmap, out);
}

// Round 3
// 399.774 us; speedup vs baseline: 1.0296x; 1.0296x over previous
//
#include <hip/hip_runtime.h>
#include <hip/hip_bf16.h>
#include <math.h>

// Problem shape (fixed by reference)
#define B  32
#define C  512
#define HW 3136      // 56*56
#define HW4 784      // HW/4 float4 per channel
#define HID 32       // C/16
#define K  256       // C/2, top-k

typedef float vfloat4 __attribute__((ext_vector_type(4)));

// ---------------------------------------------------------------------------
// Kernel 1: per-(b,c) mean+max pooling. One block per channel.
// x stays cache-resident (no nt) so scale_kernel can re-read it from L3.
// ---------------------------------------------------------------------------
__global__ __launch_bounds__(256) void pool_kernel(const float* __restrict__ x,
                                                   float* __restrict__ y) {
    const int bc = blockIdx.x;
    const float4* xp = (const float4*)(x + (size_t)bc * HW);
    float sum = 0.f;
    float mx  = -INFINITY;
    for (int i = threadIdx.x; i < HW4; i += 256) {
        float4 v = xp[i];
        sum += (v.x + v.y) + (v.z + v.w);
        mx = fmaxf(mx, fmaxf(fmaxf(v.x, v.y), fmaxf(v.z, v.w)));
    }
    for (int off = 32; off > 0; off >>= 1) {
        sum += __shfl_down(sum, off, 64);
        mx   = fmaxf(mx, __shfl_down(mx, off, 64));
    }
    __shared__ float ssum[4], smx[4];
    const int wave = threadIdx.x >> 6;
    const int lane = threadIdx.x & 63;
    if (lane == 0) { ssum[wave] = sum; smx[wave] = mx; }
    __syncthreads();
    if (threadIdx.x == 0) {
        float s = (ssum[0] + ssum[1]) + (ssum[2] + ssum[3]);
        float m = fmaxf(fmaxf(smx[0], smx[1]), fmaxf(smx[2], smx[3]));
        y[bc] = s * (1.0f / (float)HW) + m;
    }
}

// ---------------------------------------------------------------------------
// Kernel 2: per-batch-row MLP + sigmoid + kth-largest threshold + final map.
// One block (256 threads) per batch row; 32 blocks total.
// ---------------------------------------------------------------------------
__global__ __launch_bounds__(256) void mlp_kernel(const float* __restrict__ y,
                                                  const float* __restrict__ w1,
                                                  const float* __restrict__ b1,
                                                  const float* __restrict__ prelu_a,
                                                  const float* __restrict__ w2,
                                                  const float* __restrict__ b2,
                                                  const float* __restrict__ rnd,
                                                  float* __restrict__ fmap) {
    const int b = blockIdx.x;
    const int t = threadIdx.x;

    __shared__ __align__(16) float ylds[C];
    __shared__ float hlds[HID];
    __shared__ __align__(16) float y2[C];
    __shared__ float hpart[256];
    __shared__ float thresh;

    ylds[t]       = y[b * C + t];
    ylds[t + 256] = y[b * C + t + 256];
    __syncthreads();

    // h[j] = sum_c y[c] * w1[c][j] + b1[j], PReLU.
    // thread t owns (j = t&31, chunk = t>>5); 8 chunks of 64.
    {
        const int j = t & 31;
        const int chunk = t >> 5;
        float acc = 0.f;
        const int c0 = chunk * 64;
        #pragma unroll 8
        for (int c = c0; c < c0 + 64; ++c)
            acc += ylds[c] * w1[c * HID + j];
        hpart[t] = acc;
        __syncthreads();
        if (t < HID) {
            float a = ((hpart[t]       + hpart[t + 32]) + (hpart[t + 64]  + hpart[t + 96])) +
                      ((hpart[t + 128] + hpart[t + 160]) + (hpart[t + 192] + hpart[t + 224]));
            a += b1[t];
            const float al = prelu_a[0];
            hlds[t] = (a >= 0.f) ? a : al * a;
        }
    }
    __syncthreads();

    // y2[c] = sigmoid(h . w2[:,c] + b2[c]); thread t owns c = t and c = t+256
    {
        float acc0 = b2[t];
        float acc1 = b2[t + 256];
        #pragma unroll
        for (int j = 0; j < HID; ++j) {
            const float hj = hlds[j];
            acc0 += hj * w2[j * C + t];
            acc1 += hj * w2[j * C + t + 256];
        }
        y2[t]       = 1.f / (1.f + expf(-acc0));
        y2[t + 256] = 1.f / (1.f + expf(-acc1));
    }
    __syncthreads();

    // kth-largest via rank selection with index tie-break, both candidates in
    // one pass over y2 read as float4 LDS broadcasts (128 ds_read_b128).
    {
        const int cA = t, cB = t + 256;
        const float vA = y2[cA], vB = y2[cB];
        int rankA = 0, rankB = 0;
        const float4* y2v = (const float4*)y2;
        #pragma unroll 8
        for (int jj = 0; jj < C / 4; ++jj) {
            const float4 u = y2v[jj];
            const int j0 = jj * 4;
            rankA += (u.x > vA) || (u.x == vA && (j0    ) < cA);
            rankA += (u.y > vA) || (u.y == vA && (j0 + 1) < cA);
            rankA += (u.z > vA) || (u.z == vA && (j0 + 2) < cA);
            rankA += (u.w > vA) || (u.w == vA && (j0 + 3) < cA);
            rankB += (u.x > vB) || (u.x == vB && (j0    ) < cB);
            rankB += (u.y > vB) || (u.y == vB && (j0 + 1) < cB);
            rankB += (u.z > vB) || (u.z == vB && (j0 + 2) < cB);
            rankB += (u.w > vB) || (u.w == vB && (j0 + 3) < cB);
        }
        if (rankA == K - 1) thresh = vA;
        if (rankB == K - 1) thresh = vB;
    }
    __syncthreads();

    const float th = thresh;
    {
        const float vA = y2[t], vB = y2[t + 256];
        const float rbA = (rnd[b * C + t]       - 0.5f < 0.f) ? 1.f : 0.f;
        const float rbB = (rnd[b * C + t + 256] - 0.5f < 0.f) ? 1.f : 0.f;
        const float mkA = (vA - th < 0.f) ? 1.f : 0.f;
        const float mkB = (vB - th < 0.f) ? 1.f : 0.f;
        fmap[b * C + t]       = (rbA != 0.f) ? (mkA * vA) : vA;
        fmap[b * C + t + 256] = (rbB != 0.f) ? (mkB * vB) : vB;
    }
}

// ---------------------------------------------------------------------------
// Kernel 3: out = x * fmap[channel], one float4 per thread.
//  - fmap==0 channels (~25%): skip the x load entirely, store zeros.
//  - nontemporal stores for out: keep x L3-resident (x = 196 MiB < 256 MiB L3).
// ---------------------------------------------------------------------------
__global__ __launch_bounds__(256) void scale_kernel(const float* __restrict__ x,
                                                    const float* __restrict__ fmap,
                                                    float* __restrict__ out) {
    const int i4 = blockIdx.x * 256 + threadIdx.x;
    const int ch = i4 / HW4;               // magic-multiply division by 784
    const float s = fmap[ch];
    vfloat4 r;
    if (s == 0.f) {
        r = (vfloat4)0.f;
    } else {
        vfloat4 v = ((const vfloat4*)x)[i4];
        r = v * s;
    }
    __builtin_nontemporal_store(r, (vfloat4*)out + i4);
}

extern "C" void kernel_launch(void* const* d_in, const int* in_sizes, int n_in,
                              void* d_out, int out_size, void* d_ws, size_t ws_size,
                              hipStream_t stream) {
    const float* x       = (const float*)d_in[0];
    const float* w1      = (const float*)d_in[1];
    const float* b1      = (const float*)d_in[2];
    const float* prelu_a = (const float*)d_in[3];
    const float* w2      = (const float*)d_in[4];
    const float* b2      = (const float*)d_in[5];
    const float* rnd     = (const float*)d_in[6];
    float* out = (float*)d_out;

    float* y    = (float*)d_ws;            // B*C floats
    float* fmap = y + B * C;               // B*C floats

    pool_kernel<<<B * C, 256, 0, stream>>>(x, y);
    mlp_kernel<<<B, 256, 0, stream>>>(y, w1, b1, prelu_a, w2, b2, rnd, fmap);
    scale_kernel<<<(B * C * HW4) / 256, 256, 0, stream>>>(x, fmap, out);
}